// Round 13
// baseline (703.265 us; speedup 1.0000x reference)
//
#include <hip/hip_runtime.h>
#include <math.h>

#define N_NODES 10000
#define N_EDGES 160000
#define D 512
#define SLOTS 64

// =============================================================== A
// blocks [0,8): redundantly compute V_b[k,c]=sum_n W2_b[k][n]*F_b[n][c] into
//              LDS, then emit U slice [bid*128,(bid+1)*128): U_b=W1_b.V_b.
//              block 0 wave 0 additionally: beta1_b = b1_b.V_b, cvec.
// blocks [8,87): zero fpos0|fpos1 (contiguous 2*N ints)

__global__ __launch_bounds__(256) void a_fold_zero(
    const float* __restrict__ W1i, const float* __restrict__ W1o,
    const float* __restrict__ W2i, const float* __restrict__ W2o,
    const float* __restrict__ b1i, const float* __restrict__ b1o,
    const float* __restrict__ b2i, const float* __restrict__ b2o,
    const float* __restrict__ fcw, const float* __restrict__ fcb,
    float2* __restrict__ U, float2* __restrict__ beta1, float2* __restrict__ cvec,
    int* __restrict__ fpos) {
    int bid = blockIdx.x;
    if (bid >= 8) {
        int i = (bid - 8) * 256 + threadIdx.x;
        if (i < 2 * N_NODES) fpos[i] = 0;
        return;
    }
    __shared__ float2 Vs[1024];
    int wave = threadIdx.x >> 6, lane = threadIdx.x & 63;
    // ---- V (redundant per block)
    for (int idx = wave; idx < 1024; idx += 4) {
        int b = idx >> 9, k = idx & 511;
        const float* W = b ? W2o : W2i;
        const float* F = fcw + b * 1024;
        float v0 = 0.f, v1 = 0.f;
        for (int n = lane; n < 512; n += 64) {
            float w = W[k * 512 + n];
            v0 += w * F[2 * n];
            v1 += w * F[2 * n + 1];
        }
#pragma unroll
        for (int off = 32; off; off >>= 1) {
            v0 += __shfl_down(v0, off);
            v1 += __shfl_down(v1, off);
        }
        if (lane == 0) Vs[idx] = make_float2(v0, v1);
    }
    __syncthreads();
    // ---- U slice
    for (int u = 0; u < 32; ++u) {
        int uidx = bid * 128 + wave * 32 + u;
        int b = uidx >> 9, j = uidx & 511;
        const float* W = b ? W1o : W1i;
        float u0 = 0.f, u1 = 0.f;
        for (int k = lane; k < 512; k += 64) {
            float w = W[j * 512 + k];
            float2 v = Vs[b * 512 + k];
            u0 += w * v.x;
            u1 += w * v.y;
        }
#pragma unroll
        for (int off = 32; off; off >>= 1) {
            u0 += __shfl_down(u0, off);
            u1 += __shfl_down(u1, off);
        }
        if (lane == 0) U[uidx] = make_float2(u0, u1);
    }
    // ---- beta1 + cvec (block 0, wave 0)
    if (bid == 0 && wave == 0) {
        float a00 = 0.f, a01 = 0.f, a10 = 0.f, a11 = 0.f, c0 = 0.f, c1 = 0.f;
        for (int k = lane; k < 512; k += 64) {
            float2 v0 = Vs[k], v1 = Vs[512 + k];
            a00 += b1i[k] * v0.x;
            a01 += b1i[k] * v0.y;
            a10 += b1o[k] * v1.x;
            a11 += b1o[k] * v1.y;
            c0 += b2i[k] * fcw[2 * k] + b2o[k] * fcw[2 * (512 + k)];
            c1 += b2i[k] * fcw[2 * k + 1] + b2o[k] * fcw[2 * (512 + k) + 1];
        }
#pragma unroll
        for (int off = 32; off; off >>= 1) {
            a00 += __shfl_down(a00, off);
            a01 += __shfl_down(a01, off);
            a10 += __shfl_down(a10, off);
            a11 += __shfl_down(a11, off);
            c0 += __shfl_down(c0, off);
            c1 += __shfl_down(c1, off);
        }
        if (lane == 0) {
            beta1[0] = make_float2(a00, a01);
            beta1[1] = make_float2(a10, a11);
            *cvec = make_float2(c0 + fcb[0], c1 + fcb[1]);
        }
    }
}

// =============================================================== B
// blocks [0,1250): slot-CSR fill (fpos counts degree as side effect)
// blocks [1250,3750): r_b[i] = TE_b[i,:] @ U_b  (UNscaled; wave per node)

__global__ __launch_bounds__(256) void b_fill_r(
    const int* __restrict__ ein, const int* __restrict__ eout,
    int* __restrict__ fpos0, int* __restrict__ fpos1,
    int* __restrict__ es0, int* __restrict__ es1,
    const float* __restrict__ x, const float* __restrict__ t,
    const float* __restrict__ w0, const float* __restrict__ b0,
    const float* __restrict__ w1, const float* __restrict__ b1,
    const float2* __restrict__ U,
    float2* __restrict__ r0, float2* __restrict__ r1) {
    int bid = blockIdx.x;
    if (bid < 1250) {
        int i = bid * 256 + threadIdx.x;
        int br = i >= N_EDGES;
        int e = i - br * N_EDGES;
        const int* ei = br ? eout : ein;
        int s = ei[e], d = ei[N_EDGES + e];
        int pos = atomicAdd(&(br ? fpos1 : fpos0)[d], 1);
        if (pos < SLOTS) (br ? es1 : es0)[d * SLOTS + pos] = s;
        return;
    }
    int node = (bid - 1250) * 4 + (threadIdx.x >> 6);
    int lane = threadIdx.x & 63;
    int j0 = lane * 8;
    float tv = t[node];
    float4 xa = *(const float4*)&x[(size_t)node * D + j0];
    float4 xb = *(const float4*)&x[(size_t)node * D + j0 + 4];
    float xv[8] = {xa.x, xa.y, xa.z, xa.w, xb.x, xb.y, xb.z, xb.w};
    float s00 = 0.f, s01 = 0.f, s10 = 0.f, s11 = 0.f;
#pragma unroll
    for (int j = 0; j < 8; ++j) {
        float xx = xv[j];
        float te0 = xx + __cosf(tv * w0[j0 + j] + b0[j0 + j]);
        float te1 = xx + __cosf(tv * w1[j0 + j] + b1[j0 + j]);
        float2 u0 = U[j0 + j];
        float2 u1 = U[512 + j0 + j];
        s00 += te0 * u0.x;
        s01 += te0 * u0.y;
        s10 += te1 * u1.x;
        s11 += te1 * u1.y;
    }
#pragma unroll
    for (int off = 32; off; off >>= 1) {
        s00 += __shfl_down(s00, off);
        s01 += __shfl_down(s01, off);
        s10 += __shfl_down(s10, off);
        s11 += __shfl_down(s11, off);
    }
    if (lane == 0) {
        r0[node] = make_float2(s00, s01);
        r1[node] = make_float2(s10, s11);
    }
}

// =============================================================== C
// pw_b[i] = dinv_i * (dvd*sum_s dinv_s*r[s] + dvd^2*r[i] + beta1_b), dvd=dinv_i
// dinv computed on the fly from fpos. wave per node; half-wave per branch.

__global__ __launch_bounds__(256) void c_pgather(
    const float2* __restrict__ r0, const float2* __restrict__ r1,
    const int* __restrict__ fpos0, const int* __restrict__ fpos1,
    const int* __restrict__ es0, const int* __restrict__ es1,
    const float2* __restrict__ beta1,
    float2* __restrict__ p0, float2* __restrict__ p1) {
    int node = blockIdx.x * 4 + (threadIdx.x >> 6);
    int lane = threadIdx.x & 63;
    int half = lane >> 5, hl = lane & 31;
    const float2* rr = half ? r1 : r0;
    const int* es = half ? es1 : es0;
    const int* fp = half ? fpos1 : fpos0;
    int cnt = fp[node];
    int cl = cnt > SLOTS ? SLOTS : cnt;
    float a0 = 0.f, a1 = 0.f;
    for (int j = hl; j < cl; j += 32) {
        int s = es[node * SLOTS + j];
        float dvs = rsqrtf((float)fp[s] + 1.0f);
        float2 v = rr[s];
        a0 += dvs * v.x;
        a1 += dvs * v.y;
    }
#pragma unroll
    for (int m = 16; m; m >>= 1) {
        a0 += __shfl_xor(a0, m);
        a1 += __shfl_xor(a1, m);
    }
    if (hl == 0) {
        float dvd = rsqrtf((float)cnt + 1.0f);
        float2 rv = rr[node];
        float2 bb = beta1[half];
        float d2 = dvd * dvd;
        float pfx = dvd * a0 + d2 * rv.x + bb.x;
        float pfy = dvd * a1 + d2 * rv.y + bb.y;
        (half ? p1 : p0)[node] = make_float2(dvd * pfx, dvd * pfy);
    }
}

// =============================================================== D
// z = sum_b dvd_b*(sum_s pw_b[s] + pw_b[i]) + cvec ; log_softmax

__global__ __launch_bounds__(256) void d_zlsm(
    const float2* __restrict__ p0, const float2* __restrict__ p1,
    const int* __restrict__ fpos0, const int* __restrict__ fpos1,
    const int* __restrict__ es0, const int* __restrict__ es1,
    const float2* __restrict__ cvec, float* __restrict__ out) {
    int node = blockIdx.x * 4 + (threadIdx.x >> 6);
    int lane = threadIdx.x & 63;
    int half = lane >> 5, hl = lane & 31;
    const float2* pp = half ? p1 : p0;
    const int* es = half ? es1 : es0;
    const int* fp = half ? fpos1 : fpos0;
    int cnt = fp[node];
    int cl = cnt > SLOTS ? SLOTS : cnt;
    float a0 = 0.f, a1 = 0.f;
    for (int j = hl; j < cl; j += 32) {
        float2 v = pp[es[node * SLOTS + j]];
        a0 += v.x;
        a1 += v.y;
    }
#pragma unroll
    for (int m = 16; m; m >>= 1) {
        a0 += __shfl_xor(a0, m);
        a1 += __shfl_xor(a1, m);
    }
    float dvd = rsqrtf((float)cnt + 1.0f);
    float2 ps = pp[node];
    a0 = dvd * (a0 + ps.x);
    a1 = dvd * (a1 + ps.y);
    a0 += __shfl_xor(a0, 32);
    a1 += __shfl_xor(a1, 32);
    if (lane == 0) {
        float2 cv = *cvec;
        float z0 = a0 + cv.x, z1 = a1 + cv.y;
        float m = fmaxf(z0, z1);
        float l2 = m + logf(expf(z0 - m) + expf(z1 - m));
        out[node * 2 + 0] = z0 - l2;
        out[node * 2 + 1] = z1 - l2;
    }
}

// ---------------------------------------------------------------- launch

extern "C" void kernel_launch(void* const* d_in, const int* in_sizes, int n_in,
                              void* d_out, int out_size, void* d_ws, size_t ws_size,
                              hipStream_t stream) {
    const float* x        = (const float*)d_in[0];
    const int*   ein      = (const int*)d_in[1];
    const int*   eout     = (const int*)d_in[2];
    const float* t        = (const float*)d_in[3];
    const float* te_w[2]  = {(const float*)d_in[4], (const float*)d_in[10]};
    const float* te_b[2]  = {(const float*)d_in[5], (const float*)d_in[11]};
    const float* W1[2]    = {(const float*)d_in[6], (const float*)d_in[12]};
    const float* b1[2]    = {(const float*)d_in[7], (const float*)d_in[13]};
    const float* W2[2]    = {(const float*)d_in[8], (const float*)d_in[14]};
    const float* b2[2]    = {(const float*)d_in[9], (const float*)d_in[15]};
    const float* fc_w     = (const float*)d_in[16];
    const float* fc_b     = (const float*)d_in[17];
    float* out = (float*)d_out;

    char* wp = (char*)d_ws;
    auto carve = [&](size_t bytes) {
        void* r = (void*)wp;
        wp += ((bytes + 255) / 256) * 256;
        return r;
    };
    float2* U     = (float2*)carve((size_t)1024 * 8);
    float2* beta1 = (float2*)carve(2 * 8);
    float2* cvec  = (float2*)carve(8);
    float2* rbuf[2];
    rbuf[0] = (float2*)carve((size_t)N_NODES * 8);
    rbuf[1] = (float2*)carve((size_t)N_NODES * 8);
    float2* pbuf[2];
    pbuf[0] = (float2*)carve((size_t)N_NODES * 8);
    pbuf[1] = (float2*)carve((size_t)N_NODES * 8);
    int* fpos = (int*)carve((size_t)2 * N_NODES * 4);  // fpos0|fpos1 contiguous
    int *fpos0 = fpos, *fpos1 = fpos + N_NODES;
    int* esrc[2];
    esrc[0] = (int*)carve((size_t)N_NODES * SLOTS * 4);
    esrc[1] = (int*)carve((size_t)N_NODES * SLOTS * 4);

    a_fold_zero<<<87, 256, 0, stream>>>(W1[0], W1[1], W2[0], W2[1],
                                        b1[0], b1[1], b2[0], b2[1],
                                        fc_w, fc_b, U, beta1, cvec, fpos);
    b_fill_r<<<3750, 256, 0, stream>>>(ein, eout, fpos0, fpos1,
                                       esrc[0], esrc[1], x, t,
                                       te_w[0], te_b[0], te_w[1], te_b[1],
                                       U, rbuf[0], rbuf[1]);
    c_pgather<<<2500, 256, 0, stream>>>(rbuf[0], rbuf[1], fpos0, fpos1,
                                        esrc[0], esrc[1], beta1,
                                        pbuf[0], pbuf[1]);
    d_zlsm<<<2500, 256, 0, stream>>>(pbuf[0], pbuf[1], fpos0, fpos1,
                                     esrc[0], esrc[1], cvec, out);
}

// Round 14
// 51.376 us; speedup vs baseline: 13.6885x; 13.6885x over previous
//
#include <hip/hip_runtime.h>
#include <math.h>

#define N_NODES 10000
#define N_EDGES 160000
#define D 512
#define SLOTS 64

// =============================================================== K1
// blocks [0,256): V_b[k,c] = sum_n W2_b[k][n]*F_b[n][c]  (wave per (b,k))
// blocks [256,335): zero fpos0|fpos1 (contiguous 2*N ints)

__global__ __launch_bounds__(256) void k1_vproj_zero(
    const float* __restrict__ W2i, const float* __restrict__ W2o,
    const float* __restrict__ fcw, float2* __restrict__ V,
    int* __restrict__ fpos) {
    int bid = blockIdx.x;
    if (bid < 256) {
        int wv = bid * 4 + (threadIdx.x >> 6);
        int lane = threadIdx.x & 63;
        int b = wv >> 9, k = wv & 511;
        const float* W = b ? W2o : W2i;
        const float* F = fcw + b * 1024;
        float v0 = 0.f, v1 = 0.f;
        for (int n = lane; n < 512; n += 64) {
            float w = W[k * 512 + n];
            v0 += w * F[2 * n];
            v1 += w * F[2 * n + 1];
        }
#pragma unroll
        for (int off = 32; off; off >>= 1) {
            v0 += __shfl_down(v0, off);
            v1 += __shfl_down(v1, off);
        }
        if (lane == 0) V[wv] = make_float2(v0, v1);
    } else {
        int i = (bid - 256) * 256 + threadIdx.x;
        if (i < 2 * N_NODES) fpos[i] = 0;
    }
}

// =============================================================== K2
// blocks [0,1250): slot-CSR fill (fpos counts degree as side effect)
// blocks [1250,1508): U_b = W1_b.V_b ; tail wave: beta1, cvec

__global__ __launch_bounds__(256) void k2_fill_uproj(
    const int* __restrict__ ein, const int* __restrict__ eout,
    int* __restrict__ fpos0, int* __restrict__ fpos1,
    int* __restrict__ es0, int* __restrict__ es1,
    const float* __restrict__ W1i, const float* __restrict__ W1o,
    const float2* __restrict__ V,
    const float* __restrict__ b1i, const float* __restrict__ b1o,
    const float* __restrict__ b2i, const float* __restrict__ b2o,
    const float* __restrict__ fcw, const float* __restrict__ fcb,
    float2* __restrict__ U, float2* __restrict__ beta1, float2* __restrict__ cvec) {
    int bid = blockIdx.x;
    if (bid < 1250) {
        int i = bid * 256 + threadIdx.x;
        int br = i >= N_EDGES;
        int e = i - br * N_EDGES;
        const int* ei = br ? eout : ein;
        int s = ei[e], d = ei[N_EDGES + e];
        int pos = atomicAdd(&(br ? fpos1 : fpos0)[d], 1);
        if (pos < SLOTS) (br ? es1 : es0)[d * SLOTS + pos] = s;
        return;
    }
    int wv = (bid - 1250) * 4 + (threadIdx.x >> 6);
    int lane = threadIdx.x & 63;
    if (wv < 1024) {
        int b = wv >> 9, j = wv & 511;
        const float* W = b ? W1o : W1i;
        const float2* Vb = V + b * 512;
        float u0 = 0.f, u1 = 0.f;
        for (int k = lane; k < 512; k += 64) {
            float w = W[j * 512 + k];
            float2 v = Vb[k];
            u0 += w * v.x;
            u1 += w * v.y;
        }
#pragma unroll
        for (int off = 32; off; off >>= 1) {
            u0 += __shfl_down(u0, off);
            u1 += __shfl_down(u1, off);
        }
        if (lane == 0) U[wv] = make_float2(u0, u1);
    } else if (wv == 1024) {
        float a00 = 0.f, a01 = 0.f, a10 = 0.f, a11 = 0.f, c0 = 0.f, c1 = 0.f;
        for (int k = lane; k < 512; k += 64) {
            float2 v0 = V[k], v1 = V[512 + k];
            a00 += b1i[k] * v0.x;
            a01 += b1i[k] * v0.y;
            a10 += b1o[k] * v1.x;
            a11 += b1o[k] * v1.y;
            c0 += b2i[k] * fcw[2 * k] + b2o[k] * fcw[2 * (512 + k)];
            c1 += b2i[k] * fcw[2 * k + 1] + b2o[k] * fcw[2 * (512 + k) + 1];
        }
#pragma unroll
        for (int off = 32; off; off >>= 1) {
            a00 += __shfl_down(a00, off);
            a01 += __shfl_down(a01, off);
            a10 += __shfl_down(a10, off);
            a11 += __shfl_down(a11, off);
            c0 += __shfl_down(c0, off);
            c1 += __shfl_down(c1, off);
        }
        if (lane == 0) {
            beta1[0] = make_float2(a00, a01);
            beta1[1] = make_float2(a10, a11);
            *cvec = make_float2(c0 + fcb[0], c1 + fcb[1]);
        }
    }
}

// =============================================================== K3
// rw_b[i] = dinv_b[i] * (TE_b[i,:] @ U_b), dinv from slot counts (wave/node)

__global__ __launch_bounds__(256) void k3_r(
    const float* __restrict__ x, const float* __restrict__ t,
    const float* __restrict__ w0, const float* __restrict__ b0,
    const float* __restrict__ w1, const float* __restrict__ b1,
    const float2* __restrict__ U,
    const int* __restrict__ fpos0, const int* __restrict__ fpos1,
    float2* __restrict__ r0, float2* __restrict__ r1,
    float* __restrict__ dv0, float* __restrict__ dv1) {
    int node = blockIdx.x * 4 + (threadIdx.x >> 6);
    int lane = threadIdx.x & 63;
    int j0 = lane * 8;
    float tv = t[node];
    float4 xa = *(const float4*)&x[(size_t)node * D + j0];
    float4 xb = *(const float4*)&x[(size_t)node * D + j0 + 4];
    float xv[8] = {xa.x, xa.y, xa.z, xa.w, xb.x, xb.y, xb.z, xb.w};
    float s00 = 0.f, s01 = 0.f, s10 = 0.f, s11 = 0.f;
#pragma unroll
    for (int j = 0; j < 8; ++j) {
        float xx = xv[j];
        float te0 = xx + __cosf(tv * w0[j0 + j] + b0[j0 + j]);
        float te1 = xx + __cosf(tv * w1[j0 + j] + b1[j0 + j]);
        float2 u0 = U[j0 + j];
        float2 u1 = U[512 + j0 + j];
        s00 += te0 * u0.x;
        s01 += te0 * u0.y;
        s10 += te1 * u1.x;
        s11 += te1 * u1.y;
    }
#pragma unroll
    for (int off = 32; off; off >>= 1) {
        s00 += __shfl_down(s00, off);
        s01 += __shfl_down(s01, off);
        s10 += __shfl_down(s10, off);
        s11 += __shfl_down(s11, off);
    }
    if (lane == 0) {
        float da = rsqrtf((float)fpos0[node] + 1.0f);
        float db = rsqrtf((float)fpos1[node] + 1.0f);
        dv0[node] = da;
        dv1[node] = db;
        r0[node] = make_float2(da * s00, da * s01);
        r1[node] = make_float2(db * s10, db * s11);
    }
}

// =============================================================== K4
// pw_b[i] = dvd*beta1_b + dvd^2*(sum_{s in N} rw_b[s] + rw_b[i])
// 16 lanes per (node, branch): 2 nodes per wave, 8 per block.

__global__ __launch_bounds__(256) void k4_pgather(
    const float2* __restrict__ r0, const float2* __restrict__ r1,
    const int* __restrict__ fpos0, const int* __restrict__ fpos1,
    const int* __restrict__ es0, const int* __restrict__ es1,
    const float* __restrict__ dv0, const float* __restrict__ dv1,
    const float2* __restrict__ beta1,
    float2* __restrict__ p0, float2* __restrict__ p1) {
    int node = blockIdx.x * 8 + (threadIdx.x >> 5);
    int sub = threadIdx.x & 31;
    int half = sub >> 4, hl = sub & 15;
    const float2* rr = half ? r1 : r0;
    const int* es = half ? es1 : es0;
    int cnt = (half ? fpos1 : fpos0)[node];
    int cl = cnt > SLOTS ? SLOTS : cnt;
    float a0 = 0.f, a1 = 0.f;
    for (int j = hl; j < cl; j += 16) {
        float2 v = rr[es[node * SLOTS + j]];
        a0 += v.x;
        a1 += v.y;
    }
#pragma unroll
    for (int m = 8; m; m >>= 1) {
        a0 += __shfl_xor(a0, m);
        a1 += __shfl_xor(a1, m);
    }
    if (hl == 0) {
        float dvd = (half ? dv1 : dv0)[node];
        float2 rv = rr[node];
        float2 bb = beta1[half];
        float d2 = dvd * dvd;
        (half ? p1 : p0)[node] = make_float2(dvd * bb.x + d2 * (a0 + rv.x),
                                             dvd * bb.y + d2 * (a1 + rv.y));
    }
}

// =============================================================== K5
// z = sum_b dvd_b*(sum_{s in N_b} pw_b[s] + pw_b[i]) + cvec ; log_softmax
// 16 lanes per (node, branch): 2 nodes per wave.

__global__ __launch_bounds__(256) void k5_zlsm(
    const float2* __restrict__ p0, const float2* __restrict__ p1,
    const int* __restrict__ fpos0, const int* __restrict__ fpos1,
    const int* __restrict__ es0, const int* __restrict__ es1,
    const float* __restrict__ dv0, const float* __restrict__ dv1,
    const float2* __restrict__ cvec, float* __restrict__ out) {
    int node = blockIdx.x * 8 + (threadIdx.x >> 5);
    int sub = threadIdx.x & 31;
    int half = sub >> 4, hl = sub & 15;
    const float2* pp = half ? p1 : p0;
    const int* es = half ? es1 : es0;
    int cnt = (half ? fpos1 : fpos0)[node];
    int cl = cnt > SLOTS ? SLOTS : cnt;
    float a0 = 0.f, a1 = 0.f;
    for (int j = hl; j < cl; j += 16) {
        float2 v = pp[es[node * SLOTS + j]];
        a0 += v.x;
        a1 += v.y;
    }
#pragma unroll
    for (int m = 8; m; m >>= 1) {
        a0 += __shfl_xor(a0, m);
        a1 += __shfl_xor(a1, m);
    }
    float dvd = (half ? dv1 : dv0)[node];
    float2 ps = pp[node];
    a0 = dvd * (a0 + ps.x);
    a1 = dvd * (a1 + ps.y);
    a0 += __shfl_xor(a0, 16);
    a1 += __shfl_xor(a1, 16);
    if (sub == 0) {
        float2 cv = *cvec;
        float z0 = a0 + cv.x, z1 = a1 + cv.y;
        float m = fmaxf(z0, z1);
        float l2 = m + logf(expf(z0 - m) + expf(z1 - m));
        out[node * 2 + 0] = z0 - l2;
        out[node * 2 + 1] = z1 - l2;
    }
}

// ---------------------------------------------------------------- launch

extern "C" void kernel_launch(void* const* d_in, const int* in_sizes, int n_in,
                              void* d_out, int out_size, void* d_ws, size_t ws_size,
                              hipStream_t stream) {
    const float* x        = (const float*)d_in[0];
    const int*   ein      = (const int*)d_in[1];
    const int*   eout     = (const int*)d_in[2];
    const float* t        = (const float*)d_in[3];
    const float* te_w[2]  = {(const float*)d_in[4], (const float*)d_in[10]};
    const float* te_b[2]  = {(const float*)d_in[5], (const float*)d_in[11]};
    const float* W1[2]    = {(const float*)d_in[6], (const float*)d_in[12]};
    const float* b1[2]    = {(const float*)d_in[7], (const float*)d_in[13]};
    const float* W2[2]    = {(const float*)d_in[8], (const float*)d_in[14]};
    const float* b2[2]    = {(const float*)d_in[9], (const float*)d_in[15]};
    const float* fc_w     = (const float*)d_in[16];
    const float* fc_b     = (const float*)d_in[17];
    float* out = (float*)d_out;

    char* wp = (char*)d_ws;
    auto carve = [&](size_t bytes) {
        void* r = (void*)wp;
        wp += ((bytes + 255) / 256) * 256;
        return r;
    };
    float2* V     = (float2*)carve((size_t)1024 * 8);
    float2* U     = (float2*)carve((size_t)1024 * 8);
    float2* beta1 = (float2*)carve(2 * 8);
    float2* cvec  = (float2*)carve(8);
    float2* rbuf[2];
    rbuf[0] = (float2*)carve((size_t)N_NODES * 8);
    rbuf[1] = (float2*)carve((size_t)N_NODES * 8);
    float2* pbuf[2];
    pbuf[0] = (float2*)carve((size_t)N_NODES * 8);
    pbuf[1] = (float2*)carve((size_t)N_NODES * 8);
    int* fpos = (int*)carve((size_t)2 * N_NODES * 4);  // fpos0|fpos1 contiguous
    int *fpos0 = fpos, *fpos1 = fpos + N_NODES;
    int* esrc[2];
    esrc[0] = (int*)carve((size_t)N_NODES * SLOTS * 4);
    esrc[1] = (int*)carve((size_t)N_NODES * SLOTS * 4);
    float* dinv[2];
    dinv[0] = (float*)carve(N_NODES * 4);
    dinv[1] = (float*)carve(N_NODES * 4);

    k1_vproj_zero<<<335, 256, 0, stream>>>(W2[0], W2[1], fc_w, V, fpos);
    k2_fill_uproj<<<1508, 256, 0, stream>>>(ein, eout, fpos0, fpos1,
                                            esrc[0], esrc[1],
                                            W1[0], W1[1], V, b1[0], b1[1],
                                            b2[0], b2[1], fc_w, fc_b, U, beta1, cvec);
    k3_r<<<2500, 256, 0, stream>>>(x, t, te_w[0], te_b[0], te_w[1], te_b[1],
                                   U, fpos0, fpos1, rbuf[0], rbuf[1],
                                   dinv[0], dinv[1]);
    k4_pgather<<<1250, 256, 0, stream>>>(rbuf[0], rbuf[1], fpos0, fpos1,
                                         esrc[0], esrc[1], dinv[0], dinv[1],
                                         beta1, pbuf[0], pbuf[1]);
    k5_zlsm<<<1250, 256, 0, stream>>>(pbuf[0], pbuf[1], fpos0, fpos1,
                                      esrc[0], esrc[1], dinv[0], dinv[1], cvec, out);
}